// Round 1
// baseline (107.559 us; speedup 1.0000x reference)
//
#include <hip/hip_runtime.h>
#include <math.h>

// Problem shape (fixed by harness setup_inputs): B=8, N=M=4096, D=3, fp32.
#define B_SZ 8
#define N_SZ 4096
#define M_SZ 4096

#define THREADS 256
#define PTS_PER_THREAD 4
#define PTS_PER_BLOCK (THREADS * PTS_PER_THREAD)   // 1024 query points per block
#define JTILE 512                                   // target points staged in LDS per block

// grid: x = (nq/PTS_PER_BLOCK) * (nd/JTILE), y = B, z = 2 (direction)
// ws layout: [dir0: B*N floats][dir1: B*M floats], stored as uint bit patterns
// of squared distances (bit order == float order for non-negative floats).
__global__ __launch_bounds__(THREADS)
void chamfer_min_kernel(const float* __restrict__ pred,
                        const float* __restrict__ tgt,
                        unsigned int* __restrict__ ws)
{
    const int b   = blockIdx.y;
    const int dir = blockIdx.z;

    const float* Q;   // query points  (find NN for each of these)
    const float* Db;  // database points
    int nq, nd;
    unsigned int* wsd;
    if (dir == 0) { Q = pred + (size_t)b * N_SZ * 3; Db = tgt  + (size_t)b * M_SZ * 3; nq = N_SZ; nd = M_SZ; wsd = ws + (size_t)b * N_SZ; }
    else          { Q = tgt  + (size_t)b * M_SZ * 3; Db = pred + (size_t)b * N_SZ * 3; nq = M_SZ; nd = N_SZ; wsd = ws + (size_t)B_SZ * N_SZ + (size_t)b * M_SZ; }

    const int njt   = nd / JTILE;
    const int itile = blockIdx.x / njt;
    const int jtile = blockIdx.x % njt;

    __shared__ float4 spts[JTILE];

    // Stage JTILE database points into LDS (float4: x,y,z,pad).
    const float* src = Db + (size_t)jtile * JTILE * 3;
    for (int j = threadIdx.x; j < JTILE; j += THREADS) {
        float4 p;
        p.x = src[j * 3 + 0];
        p.y = src[j * 3 + 1];
        p.z = src[j * 3 + 2];
        p.w = 0.0f;
        spts[j] = p;
    }
    __syncthreads();

    // Load 4 query points per thread into registers (coalesced across k-strides).
    float qx[PTS_PER_THREAD], qy[PTS_PER_THREAD], qz[PTS_PER_THREAD];
    float mn[PTS_PER_THREAD];
    int   qi[PTS_PER_THREAD];
#pragma unroll
    for (int k = 0; k < PTS_PER_THREAD; ++k) {
        int i = itile * PTS_PER_BLOCK + threadIdx.x + k * THREADS;
        qi[k] = i;
        qx[k] = Q[i * 3 + 0];
        qy[k] = Q[i * 3 + 1];
        qz[k] = Q[i * 3 + 2];
        mn[k] = 3.0e38f;
    }

    // Main loop: one ds_read_b128 (broadcast) amortized over 4 query points.
#pragma unroll 8
    for (int j = 0; j < JTILE; ++j) {
        float4 t = spts[j];
#pragma unroll
        for (int k = 0; k < PTS_PER_THREAD; ++k) {
            float dx = qx[k] - t.x;
            float dy = qy[k] - t.y;
            float dz = qz[k] - t.z;
            float d2 = dx * dx + dy * dy + dz * dz;
            mn[k] = fminf(mn[k], d2);
        }
    }

#pragma unroll
    for (int k = 0; k < PTS_PER_THREAD; ++k) {
        atomicMin(&wsd[qi[k]], __float_as_uint(mn[k]));
    }
}

// Sum sqrt(min_sq) * scale over the whole workspace into out[0].
__global__ __launch_bounds__(THREADS)
void chamfer_reduce_kernel(const unsigned int* __restrict__ ws,
                           float* __restrict__ out,
                           int n1, int n2, float inv1, float inv2)
{
    const int total = n1 + n2;
    float s = 0.0f;
    for (int idx = blockIdx.x * blockDim.x + threadIdx.x; idx < total;
         idx += gridDim.x * blockDim.x) {
        float d2    = __uint_as_float(ws[idx]);
        float scale = (idx < n1) ? inv1 : inv2;
        s += sqrtf(d2) * scale;
    }
    // wave64 shuffle reduction
#pragma unroll
    for (int off = 32; off > 0; off >>= 1) s += __shfl_down(s, off);
    if ((threadIdx.x & 63) == 0) atomicAdd(out, s);
}

extern "C" void kernel_launch(void* const* d_in, const int* in_sizes, int n_in,
                              void* d_out, int out_size, void* d_ws, size_t ws_size,
                              hipStream_t stream) {
    const float* pred = (const float*)d_in[0];  // [B,N,3]
    const float* tgt  = (const float*)d_in[1];  // [B,M,3]
    float* out = (float*)d_out;

    unsigned int* ws = (unsigned int*)d_ws;     // 2*B*N uints = 512 KB

    // d_out / d_ws are poisoned before every launch — re-init every call.
    hipMemsetAsync(out, 0, sizeof(float), stream);
    // 0x7F7F7F7F ~= 3.39e38f: valid "infinity" for the uint-as-float min.
    hipMemsetAsync(ws, 0x7F, (size_t)(B_SZ * N_SZ + B_SZ * M_SZ) * sizeof(unsigned int), stream);

    dim3 grid((N_SZ / PTS_PER_BLOCK) * (M_SZ / JTILE), B_SZ, 2);
    chamfer_min_kernel<<<grid, THREADS, 0, stream>>>(pred, tgt, ws);

    const int n1 = B_SZ * N_SZ, n2 = B_SZ * M_SZ;
    chamfer_reduce_kernel<<<64, THREADS, 0, stream>>>(
        ws, out, n1, n2, 1.0f / (float)n1, 1.0f / (float)n2);
}

// Round 2
// 101.405 us; speedup vs baseline: 1.0607x; 1.0607x over previous
//
#include <hip/hip_runtime.h>
#include <math.h>

// Problem shape (fixed by harness setup_inputs): B=8, N=M=4096, D=3, fp32.
#define B_SZ 8
#define N_SZ 4096
#define M_SZ 4096
#define NQ_TOT (B_SZ * N_SZ)        // 32768 queries per direction
#define TOT (2 * NQ_TOT)            // 65536 total queries

#define THREADS 256
#define QPT 8                       // queries per thread -> 4 packed f32x2 slots
#define SLOTS (QPT / 2)
#define QPB (THREADS * QPT)         // 2048 queries per block
#define JTILE 256                   // targets staged in LDS per block
#define NJT (M_SZ / JTILE)          // 16
#define ITILES (N_SZ / QPB)         // 2

typedef float f32x2 __attribute__((ext_vector_type(2)));

// Monotonic float->uint key: preserves total order under unsigned compare,
// works for negative scores. Init value for atomicMin is 0xFFFFFFFF (max).
__device__ __forceinline__ unsigned int f2key(float f) {
    unsigned int b = __float_as_uint(f);
    return ((int)b < 0) ? ~b : (b | 0x80000000u);
}
__device__ __forceinline__ float key2f(unsigned int k) {
    unsigned int b = ((int)k < 0) ? (k ^ 0x80000000u) : ~k;
    return __uint_as_float(b);
}

// score(q,t) = t^2/2 - q.t ;  argmin_t score == argmin_t |q-t|^2
// d^2 = 2*score_min + q^2  (recovered in the reduce kernel).
// grid: x = ITILES*NJT (32), y = B, z = dir;  ws keys laid out
// [dir0: B*N][dir1: B*M] as transformed uint keys.
__global__ __launch_bounds__(THREADS)
void chamfer_min_kernel(const float* __restrict__ pred,
                        const float* __restrict__ tgt,
                        unsigned int* __restrict__ keys)
{
    const int b   = blockIdx.y;
    const int dir = blockIdx.z;

    const float* Q;
    const float* Db;
    unsigned int* kd;
    if (dir == 0) { Q = pred + (size_t)b * N_SZ * 3; Db = tgt  + (size_t)b * M_SZ * 3; kd = keys + (size_t)b * N_SZ; }
    else          { Q = tgt  + (size_t)b * M_SZ * 3; Db = pred + (size_t)b * N_SZ * 3; kd = keys + (size_t)NQ_TOT + (size_t)b * M_SZ; }

    const int itile = blockIdx.x >> 4;          // / NJT
    const int jtile = blockIdx.x & (NJT - 1);

    __shared__ float4 spts[JTILE];              // x,y,z,h  (h = (x^2+y^2+z^2)/2)

    // Stage JTILE targets (one per thread; JTILE == THREADS).
    {
        const float* s = Db + (size_t)(jtile * JTILE + threadIdx.x) * 3;
        float x = s[0], y = s[1], z = s[2];
        float4 p;
        p.x = x; p.y = y; p.z = z;
        p.w = 0.5f * (x * x + y * y + z * z);
        spts[threadIdx.x] = p;
    }
    __syncthreads();

    // 8 query points per thread, negated coords packed as f32x2 (2 queries/slot).
    f32x2 qxn[SLOTS], qyn[SLOTS], qzn[SLOTS], mn[SLOTS];
    const int qbase = itile * QPB + threadIdx.x;
#pragma unroll
    for (int s = 0; s < SLOTS; ++s) {
        const int i0 = qbase + (2 * s) * THREADS;
        const int i1 = qbase + (2 * s + 1) * THREADS;
        qxn[s] = { -Q[i0 * 3 + 0], -Q[i1 * 3 + 0] };
        qyn[s] = { -Q[i0 * 3 + 1], -Q[i1 * 3 + 1] };
        qzn[s] = { -Q[i0 * 3 + 2], -Q[i1 * 3 + 2] };
        mn[s]  = { 3.0e38f, 3.0e38f };
    }

    // Inner loop: 1 broadcast ds_read_b128, then per slot 3 v_pk_fma_f32 +
    // 2 v_min_f32  ->  ~2.5 VALU insts per point-pair.
#pragma unroll 8
    for (int j = 0; j < JTILE; ++j) {
        float4 t = spts[j];
        f32x2 tx = { t.x, t.x };
        f32x2 ty = { t.y, t.y };
        f32x2 tz = { t.z, t.z };
        f32x2 th = { t.w, t.w };
#pragma unroll
        for (int s = 0; s < SLOTS; ++s) {
            f32x2 sc = th + qxn[s] * tx;   // fma
            sc += qyn[s] * ty;             // fma
            sc += qzn[s] * tz;             // fma
            mn[s].x = fminf(mn[s].x, sc.x);
            mn[s].y = fminf(mn[s].y, sc.y);
        }
    }

#pragma unroll
    for (int s = 0; s < SLOTS; ++s) {
        const int i0 = qbase + (2 * s) * THREADS;
        const int i1 = qbase + (2 * s + 1) * THREADS;
        atomicMin(&kd[i0], f2key(mn[s].x));
        atomicMin(&kd[i1], f2key(mn[s].y));
    }
}

// Single block: no global atomics, writes out[0] directly (no out memset).
__global__ __launch_bounds__(1024)
void chamfer_reduce_kernel(const unsigned int* __restrict__ keys,
                           const float* __restrict__ pred,
                           const float* __restrict__ tgt,
                           float* __restrict__ out)
{
    float s = 0.0f;
    for (int idx = threadIdx.x; idx < TOT; idx += 1024) {
        float score = key2f(keys[idx]);
        const float* p = (idx < NQ_TOT) ? (pred + (size_t)idx * 3)
                                        : (tgt + (size_t)(idx - NQ_TOT) * 3);
        float x = p[0], y = p[1], z = p[2];
        float q2 = x * x + y * y + z * z;
        float d2 = fmaxf(2.0f * score + q2, 0.0f);
        s += sqrtf(d2);
    }
#pragma unroll
    for (int off = 32; off > 0; off >>= 1) s += __shfl_down(s, off);

    __shared__ float red[16];
    const int wave = threadIdx.x >> 6;
    if ((threadIdx.x & 63) == 0) red[wave] = s;
    __syncthreads();
    if (threadIdx.x == 0) {
        float t = 0.0f;
#pragma unroll
        for (int w = 0; w < 16; ++w) t += red[w];
        // loss = (sum of all 65536 NN distances) / 32768  (since N == M)
        out[0] = t * (1.0f / (float)NQ_TOT);
    }
}

extern "C" void kernel_launch(void* const* d_in, const int* in_sizes, int n_in,
                              void* d_out, int out_size, void* d_ws, size_t ws_size,
                              hipStream_t stream) {
    const float* pred = (const float*)d_in[0];  // [B,N,3]
    const float* tgt  = (const float*)d_in[1];  // [B,M,3]
    float* out = (float*)d_out;

    unsigned int* keys = (unsigned int*)d_ws;   // TOT uints = 256 KB

    // 0xFF bytes -> key 0xFFFFFFFF == max key: valid init for uint atomicMin.
    hipMemsetAsync(keys, 0xFF, (size_t)TOT * sizeof(unsigned int), stream);

    dim3 grid(ITILES * NJT, B_SZ, 2);
    chamfer_min_kernel<<<grid, THREADS, 0, stream>>>(pred, tgt, keys);

    chamfer_reduce_kernel<<<1, 1024, 0, stream>>>(keys, pred, tgt, out);
}

// Round 3
// 80.141 us; speedup vs baseline: 1.3421x; 1.2653x over previous
//
#include <hip/hip_runtime.h>
#include <math.h>

// Problem shape (fixed by harness setup_inputs): B=8, N=M=4096, D=3, fp32.
#define B_SZ 8
#define N_SZ 4096
#define M_SZ 4096
#define NQ (B_SZ * N_SZ)            // 32768 queries per direction
#define TOT (2 * NQ)                // 65536 total queries

#define THREADS 256
#define QPT 8                       // queries per thread (4 packed f32x2 slots)
#define SLOTS (QPT / 2)
#define QPB (THREADS * QPT)         // 2048 queries per block
#define ITILES (N_SZ / QPB)         // 2
#define JTILE 256                   // targets staged in LDS per block
#define NJT (M_SZ / JTILE)          // 16 target tiles (= partials per query)

#define NBLK2 (TOT / 256)           // 256 phase-2 blocks

typedef float f32x2 __attribute__((ext_vector_type(2)));

// ws layout (floats):
//   part[g * TOT + q]  : g in [0,NJT), q in [0,TOT)   -> 4 MB
//   bsum[NBLK2]        : at offset NJT*TOT            -> 1 KB
// part value = min over target-tile g of d^2/2 for query q. Every slot is
// written by phase 1, so no ws initialization is needed (harness poison is
// irrelevant). No atomics anywhere.

// score(q,t) = t^2/2 - q.t ; after the tile loop we add q^2/2 -> d^2/2.
// grid: x = ITILES*NJT (32), y = B (8), z = dir (2)  -> 512 blocks.
__global__ __launch_bounds__(THREADS)
void chamfer_partial_kernel(const float* __restrict__ pred,
                            const float* __restrict__ tgt,
                            float* __restrict__ part)
{
    const int b   = blockIdx.y;
    const int dir = blockIdx.z;

    const float* Q;
    const float* Db;
    int qoff;
    if (dir == 0) { Q = pred + (size_t)b * N_SZ * 3; Db = tgt  + (size_t)b * M_SZ * 3; qoff = b * N_SZ; }
    else          { Q = tgt  + (size_t)b * M_SZ * 3; Db = pred + (size_t)b * N_SZ * 3; qoff = NQ + b * M_SZ; }

    const int itile = blockIdx.x >> 4;          // / NJT
    const int g     = blockIdx.x & (NJT - 1);

    __shared__ float4 sp[JTILE];                // x,y,z,h  (h = |t|^2 / 2)
    {
        const float* s = Db + (size_t)(g * JTILE + threadIdx.x) * 3;
        float x = s[0], y = s[1], z = s[2];
        sp[threadIdx.x] = make_float4(x, y, z, 0.5f * (x * x + y * y + z * z));
    }
    __syncthreads();

    // 8 queries per thread: negated coords packed 2-per-f32x2; q^2/2 kept
    // to fold in after the tile loop (so phase 2 never reads the points).
    f32x2 qxn[SLOTS], qyn[SLOTS], qzn[SLOTS], q2h[SLOTS], mn[SLOTS];
    const int qbase = itile * QPB + threadIdx.x;
#pragma unroll
    for (int s = 0; s < SLOTS; ++s) {
        const int i0 = qbase + (2 * s) * THREADS;
        const int i1 = qbase + (2 * s + 1) * THREADS;
        float x0 = Q[i0 * 3 + 0], y0 = Q[i0 * 3 + 1], z0 = Q[i0 * 3 + 2];
        float x1 = Q[i1 * 3 + 0], y1 = Q[i1 * 3 + 1], z1 = Q[i1 * 3 + 2];
        qxn[s] = { -x0, -x1 };
        qyn[s] = { -y0, -y1 };
        qzn[s] = { -z0, -z1 };
        q2h[s] = { 0.5f * (x0 * x0 + y0 * y0 + z0 * z0),
                   0.5f * (x1 * x1 + y1 * y1 + z1 * z1) };
        mn[s]  = { 3.0e38f, 3.0e38f };
    }

    // Inner loop: 1 broadcast ds_read_b128; per slot 3 pk_fma + 2 v_min_f32
    // -> ~2.5 VALU insts per point-pair.
#pragma unroll 8
    for (int j = 0; j < JTILE; ++j) {
        float4 t = sp[j];
        f32x2 tx = { t.x, t.x };
        f32x2 ty = { t.y, t.y };
        f32x2 tz = { t.z, t.z };
        f32x2 th = { t.w, t.w };
#pragma unroll
        for (int s = 0; s < SLOTS; ++s) {
            f32x2 sc = th + qxn[s] * tx;
            sc += qyn[s] * ty;
            sc += qzn[s] * tz;
            mn[s].x = fminf(mn[s].x, sc.x);
            mn[s].y = fminf(mn[s].y, sc.y);
        }
    }

    // Fold q^2/2 -> partial d^2/2; plain coalesced stores (no atomics).
    float* pg = part + (size_t)g * TOT + qoff;
#pragma unroll
    for (int s = 0; s < SLOTS; ++s) {
        f32x2 v = mn[s] + q2h[s];
        pg[qbase + (2 * s) * THREADS]     = v.x;
        pg[qbase + (2 * s + 1) * THREADS] = v.y;
    }
}

// Phase 2: one query per thread; 16 coalesced independent loads; block sum.
__global__ __launch_bounds__(256)
void chamfer_combine_kernel(const float* __restrict__ part,
                            float* __restrict__ bsum)
{
    const int q = blockIdx.x * 256 + threadIdx.x;
    float m = 3.0e38f;
#pragma unroll
    for (int g = 0; g < NJT; ++g) m = fminf(m, part[(size_t)g * TOT + q]);
    float d = sqrtf(2.0f * fmaxf(m, 0.0f));
#pragma unroll
    for (int off = 32; off > 0; off >>= 1) d += __shfl_down(d, off);
    __shared__ float r[4];
    if ((threadIdx.x & 63) == 0) r[threadIdx.x >> 6] = d;
    __syncthreads();
    if (threadIdx.x == 0) bsum[blockIdx.x] = r[0] + r[1] + r[2] + r[3];
}

// Phase 3: one wave sums the 256 block partials.
__global__ __launch_bounds__(64)
void chamfer_final_kernel(const float* __restrict__ bsum,
                          float* __restrict__ out)
{
    float s = 0.0f;
#pragma unroll
    for (int i = 0; i < NBLK2 / 64; ++i) s += bsum[threadIdx.x + i * 64];
#pragma unroll
    for (int off = 32; off > 0; off >>= 1) s += __shfl_down(s, off);
    // loss = mean(min_p2t) + mean(min_t2p) = (sum of all NN dists)/NQ  (N==M)
    if (threadIdx.x == 0) out[0] = s * (1.0f / (float)NQ);
}

extern "C" void kernel_launch(void* const* d_in, const int* in_sizes, int n_in,
                              void* d_out, int out_size, void* d_ws, size_t ws_size,
                              hipStream_t stream) {
    const float* pred = (const float*)d_in[0];  // [B,N,3]
    const float* tgt  = (const float*)d_in[1];  // [B,M,3]
    float* out = (float*)d_out;

    float* part = (float*)d_ws;                 // NJT*TOT floats = 4 MB
    float* bsum = part + (size_t)NJT * TOT;     // NBLK2 floats

    dim3 grid1(ITILES * NJT, B_SZ, 2);
    chamfer_partial_kernel<<<grid1, THREADS, 0, stream>>>(pred, tgt, part);
    chamfer_combine_kernel<<<NBLK2, 256, 0, stream>>>(part, bsum);
    chamfer_final_kernel<<<1, 64, 0, stream>>>(bsum, out);
}